// Round 16
// baseline (226.356 us; speedup 1.0000x reference)
//
#include <hip/hip_runtime.h>
#include <hip/hip_bf16.h>

typedef unsigned short ushort_t;
typedef __attribute__((ext_vector_type(4))) float f32x4;
typedef __attribute__((ext_vector_type(8))) short s16x8;

#define DEV static __device__ __forceinline__

constexpr int Bb = 2, Nn = 2048, Dd = 768, Hh = 12, FFf = 3072;
constexpr int MTOK = Bb * Nn;           // 4096
constexpr int QKVN = 3 * Dd;            // 2304

DEV unsigned short f2bf(float f) {
    union { float f; unsigned int i; } x; x.f = f;
    unsigned int r = x.i + 0x7FFFu + ((x.i >> 16) & 1u);
    return (unsigned short)(r >> 16);
}

DEV void gload16(const void* g, void* l) {
    __builtin_amdgcn_global_load_lds(
        (const __attribute__((address_space(1))) void*)g,
        (__attribute__((address_space(3))) void*)l, 16, 0, 0);
}

DEV int xcd_swz(int lin, int n) {  // n % 8 == 0 required
    return (lin & 7) * (n >> 3) + (lin >> 3);
}

DEV float gelu_fast(float x) {
    float u = x * (0.7978845608f + 0.0356774081f * x * x);
    float e = __builtin_amdgcn_exp2f(2.885390082f * u);
    float th = 1.f - 2.f / (e + 1.f);
    return 0.5f * x * (1.f + th);
}

// ---------------- all 4 weight transposes in ONE kernel ----------------
__global__ void k_transpose_all(const float* __restrict__ w_qkv, const float* __restrict__ w_out,
                                const float* __restrict__ w_ff1, const float* __restrict__ w_ff2,
                                unsigned short* __restrict__ o_qkv, unsigned short* __restrict__ o_out,
                                unsigned short* __restrict__ o_ff1, unsigned short* __restrict__ o_ff2) {
    __shared__ float t[32][33];
    int id = blockIdx.x;
    const float* in; unsigned short* out; int K, N, tid;
    if (id < 1728)      { in = w_qkv; out = o_qkv; K = 768;  N = 2304; tid = id; }
    else if (id < 2304) { in = w_out; out = o_out; K = 768;  N = 768;  tid = id - 1728; }
    else if (id < 4608) { in = w_ff1; out = o_ff1; K = 768;  N = 3072; tid = id - 2304; }
    else                { in = w_ff2; out = o_ff2; K = 3072; N = 768;  tid = id - 4608; }
    int nbx = N >> 5;
    int bx = (tid % nbx) * 32, by = (tid / nbx) * 32;
    int tx = threadIdx.x, ty = threadIdx.y;
#pragma unroll
    for (int i = 0; i < 4; i++)
        t[ty + 8 * i][tx] = in[(size_t)(by + ty + 8 * i) * N + bx + tx];
    __syncthreads();
#pragma unroll
    for (int i = 0; i < 4; i++)
        out[(size_t)(bx + ty + 8 * i) * K + by + tx] = f2bf(t[tx][ty + 8 * i]);
}

// ---------------- deterministic spatial counting sort ----------------
DEV int cell3(float x, float y, float z) {
    int cx = (int)(x * 0.5f); cx = cx > 4 ? 4 : cx;
    int cy = (int)(y * 0.5f); cy = cy > 4 ? 4 : cy;
    int cz = (int)(z * 0.5f); cz = cz > 4 ? 4 : cz;
    return (cz * 5 + cy) * 5 + cx;
}

__global__ __launch_bounds__(256) void k_sort(const float* __restrict__ coords,
                                              int* __restrict__ s2o,
                                              float4* __restrict__ c4s) {
    int b = blockIdx.y;
    int i = blockIdx.x * 4 + (threadIdx.x >> 6);
    int lane = threadIdx.x & 63;
    const float* cb = coords + (size_t)b * Nn * 3;
    float cix = cb[3 * i], ciy = cb[3 * i + 1], ciz = cb[3 * i + 2];
    int celli = cell3(cix, ciy, ciz);
    int pos = 0;
    for (int it = 0; it < Nn / 64; it++) {
        int j = it * 64 + lane;
        int cj = cell3(cb[3 * j], cb[3 * j + 1], cb[3 * j + 2]);
        bool before = (cj < celli) || (cj == celli && j < i);
        pos += __popcll(__ballot(before));
    }
    if (lane == 0) {
        s2o[b * Nn + pos] = i;
        c4s[b * Nn + pos] = make_float4(cix, ciy, ciz, 0.f);
    }
}

// ---------------- radius mask bits on SORTED coords ----------------
__global__ __launch_bounds__(256) void k_mask(const float4* __restrict__ c4s,
                                              unsigned long long* __restrict__ mb) {
    int qt = blockIdx.x, ks = blockIdx.y, b = blockIdx.z;
    __shared__ float4 ck[256];
    int t = threadIdx.x;
    ck[t] = c4s[b * Nn + ks * 256 + t];
    __syncthreads();
    int r = t >> 2, c = t & 3;
    int q = qt * 64 + r;
    float4 cq = c4s[b * Nn + q];
    unsigned long long w = 0;
#pragma unroll 8
    for (int j = 0; j < 64; j++) {
        float4 k4 = ck[c * 64 + j];
        float dx = __fsub_rn(cq.x, k4.x);
        float dy = __fsub_rn(cq.y, k4.y);
        float dz = __fsub_rn(cq.z, k4.z);
        float d2 = __fadd_rn(__fadd_rn(__fmul_rn(dx, dx), __fmul_rn(dy, dy)),
                             __fmul_rn(dz, dz));
        if (d2 <= 4.0f) w |= 1ull << j;
    }
    mb[((size_t)(b * Nn + q) << 5) + ks * 4 + c] = w;
}

// ---------------- per-64q-block live-tile union lists ----------------
__global__ __launch_bounds__(64) void k_tiles(const unsigned long long* __restrict__ mb,
                                              int* __restrict__ tl) {
    int q64 = blockIdx.x, b = blockIdx.y;
    int lane = threadIdx.x;
    unsigned long long v = 0;
    if (lane < 32) {
        const unsigned long long* base = mb + ((size_t)(b * Nn + q64 * 64) << 5) + lane;
        for (int r = 0; r < 64; r++) v |= base[(size_t)r << 5];
    }
    unsigned long long nz = __ballot(v != 0);
    int idx = __popcll(nz & ((1ull << lane) - 1));
    int* o = tl + (b * 32 + q64) * 33;
    if (v != 0) o[1 + idx] = lane;
    if (lane == 0) o[0] = __popcll(nz);
}

// ---------------- V transpose from SORTED qkv: VtT[(b*H+h)*64+d][ns] ----------------
__global__ __launch_bounds__(256) void k_vt(const unsigned short* __restrict__ qkv,
                                            unsigned short* __restrict__ VtT) {
    __shared__ unsigned short Ld[64][72];
    int ns0 = blockIdx.x * 64;
    int bh = blockIdx.y;
    int b = bh / Hh, h = bh % Hh;
    int t = threadIdx.x;
#pragma unroll
    for (int i = 0; i < 2; i++) {
        int item = t + 256 * i;
        int row = item >> 3, ch = (item & 7) * 8;
        *(s16x8*)&Ld[row][ch] =
            *(const s16x8*)(qkv + ((size_t)b * Nn + ns0 + row) * QKVN + 2 * Dd + h * 64 + ch);
    }
    __syncthreads();
    int vd = (t >> 5) * 8, vkp = (t & 31) * 2;
#pragma unroll
    for (int j = 0; j < 8; j++) {
        unsigned int pack = (unsigned int)Ld[vkp][vd + j] |
                            ((unsigned int)Ld[vkp + 1][vd + j] << 16);
        *(unsigned int*)((char*)VtT +
                         (((size_t)bh * 64 + vd + j) * Nn + ns0 + vkp) * 2) = pack;
    }
}

// ---------------- LayerNorm with row gather (sorted order) ----------------
DEV float wred_sum(float v) {
#pragma unroll
    for (int o = 32; o; o >>= 1) v += __shfl_down(v, o, 64);
    return v;
}

__global__ __launch_bounds__(256) void k_ln_g(const float* __restrict__ x,
                                              const int* __restrict__ s2o,
                                              const float* __restrict__ g,
                                              const float* __restrict__ be,
                                              unsigned short* __restrict__ out) {
    int row = blockIdx.x;
    int orig = (row & ~(Nn - 1)) | s2o[row];
    const float* xr = x + (size_t)orig * Dd;
    int t = threadIdx.x;
    float v0 = xr[t], v1 = xr[t + 256], v2 = xr[t + 512];
    float s = v0 + v1 + v2;
    float sq = v0 * v0 + v1 * v1 + v2 * v2;
    __shared__ float r1[4], r2[4];
    float ws = wred_sum(s), wq = wred_sum(sq);
    int wid = t >> 6, lane = t & 63;
    if (lane == 0) { r1[wid] = ws; r2[wid] = wq; }
    __syncthreads();
    s = r1[0] + r1[1] + r1[2] + r1[3];
    sq = r2[0] + r2[1] + r2[2] + r2[3];
    float mean = s * (1.f / Dd);
    float var = sq * (1.f / Dd) - mean * mean;
    float rs = rsqrtf(var + 1e-5f);
    unsigned short* orow = out + (size_t)row * Dd;
    orow[t]       = f2bf((v0 - mean) * rs * g[t]       + be[t]);
    orow[t + 256] = f2bf((v1 - mean) * rs * g[t + 256] + be[t + 256]);
    orow[t + 512] = f2bf((v2 - mean) * rs * g[t + 512] + be[t + 512]);
}

// ======= T3-recipe big GEMM: BM=256 x BN=128 x BK=64, 512 thr / 8 waves, dbuf 96KB =======
// Loop per K-step: stage(k+1) FIRST, then ds_read(cur)+MFMA, then ONE __syncthreads()
// (implicit vmcnt(0)+lgkmcnt(0) drain at barrier) — m230 2-phase structure.
// Wave (wr=wid>>2, wc=wid&3) owns 128x32 out: acc[8][2]; 32 MFMA/step/wave.
// Zero-conflict XOR chunk swizzle (both sides), carried from k_gemm64 (measured 0 conflicts).
template <int EPI>
__global__ __launch_bounds__(512) void k_gemm_big(const unsigned short* __restrict__ A,
                                                  const unsigned short* __restrict__ Bt,
                                                  const float* __restrict__ bias,
                                                  unsigned short* __restrict__ outp,
                                                  int M, int N, int K) {
    constexpr int BM = 256, BN = 128, BK = 64;
    __shared__ unsigned short As[2][BM * BK];   // 2 x 32KB
    __shared__ unsigned short Bs[2][BN * BK];   // 2 x 16KB
    int NB = N >> 7;
    int id = xcd_swz(blockIdx.x, gridDim.x);
    int m0 = (id / NB) * BM, n0 = (id % NB) * BN;
    int t = threadIdx.x;
    int wid = t >> 6, lane = t & 63;
    int wr = wid >> 2, wc = wid & 3;
    int lg = lane >> 4, lr = lane & 15;
    int sw = lr & 7;
    f32x4 acc[8][2] = {};

    // staging: lane -> subrow lane>>3, pre-swizzled chunk (lane&7)^(lane>>3)
    int srow = lane >> 3;
    int sch = (lane & 7) ^ srow;
    const unsigned short* Ag = A + (size_t)m0 * K + sch * 8;
    const unsigned short* Bg = Bt + (size_t)n0 * K + sch * 8;

    auto stage = [&](int buf, int kt) {
        int k0 = kt * BK;
#pragma unroll
        for (int g = 0; g < 4; g++) {   // A: 8 waves x 4 slots of 1KB
            int row = wid * 32 + g * 8 + srow;
            gload16(Ag + (size_t)row * K + k0, (char*)As[buf] + (wid * 4 + g) * 1024);
        }
#pragma unroll
        for (int g = 0; g < 2; g++) {   // B: 8 waves x 2 slots
            int row = wid * 16 + g * 8 + srow;
            gload16(Bg + (size_t)row * K + k0, (char*)Bs[buf] + (wid * 2 + g) * 1024);
        }
    };

    int NT = K / BK;
    stage(0, 0);
    __syncthreads();
    for (int k = 0; k < NT; k++) {
        int cur = k & 1;
        if (k + 1 < NT) stage(cur ^ 1, k + 1);   // issue next-tile loads BEFORE compute
        const char* Ab = (const char*)As[cur];
        const char* Bbp = (const char*)Bs[cur];
#pragma unroll
        for (int s = 0; s < 2; s++) {            // two K=32 halves
            s16x8 af[8], bfr[2];
#pragma unroll
            for (int i = 0; i < 8; i++) {
                int row = wr * 128 + i * 16 + lr;
                af[i] = *(const s16x8*)(Ab + row * 128 + (((s * 4 + lg) ^ sw) << 4));
            }
#pragma unroll
            for (int j = 0; j < 2; j++) {
                int row = wc * 32 + j * 16 + lr;
                bfr[j] = *(const s16x8*)(Bbp + row * 128 + (((s * 4 + lg) ^ sw) << 4));
            }
#pragma unroll
            for (int i = 0; i < 8; i++)
#pragma unroll
                for (int j = 0; j < 2; j++)
                    acc[i][j] = __builtin_amdgcn_mfma_f32_16x16x32_bf16(
                        af[i], bfr[j], acc[i][j], 0, 0, 0);
        }
        __syncthreads();   // drains vmcnt(0): next tile ready; buffers safe to swap
    }

    int mrow = m0 + wr * 128;
    int ncol = n0 + wc * 32;
#pragma unroll
    for (int i = 0; i < 8; i++) {
#pragma unroll
        for (int j = 0; j < 2; j++) {
            int nn = ncol + j * 16 + lr;
            float bs = bias[nn];
#pragma unroll
            for (int r = 0; r < 4; r++) {
                int mm = mrow + i * 16 + lg * 4 + r;
                float v = acc[i][j][r] + bs;
                if (EPI == 1) v = gelu_fast(v);
                outp[(size_t)mm * N + nn] = f2bf(v);
            }
        }
    }
}

// ---------------- split-K GEMM (128^2, BK=32, triple-buf, depth-2): partial f32 ----------------
template <int SPLIT>
__global__ __launch_bounds__(256) void k_gemm_sk(const unsigned short* __restrict__ A,
                                                 const unsigned short* __restrict__ Bt,
                                                 float* __restrict__ part,
                                                 int M, int N, int K) {
    constexpr int BM = 128, BN = 128, BK = 32;
    __shared__ unsigned short As[3][BM * BK];
    __shared__ unsigned short Bs[3][BN * BK];
    int NB = N >> 7, MB = M >> 7;
    int id = xcd_swz(blockIdx.x, gridDim.x);
    int nb = id % NB;
    int mbk = (id / NB) % MB;
    int kz = id / (NB * MB);
    int m0 = mbk * BM, n0 = nb * BN;
    int Kc = K / SPLIT, kb = kz * (Kc / BK);
    int t = threadIdx.x;
    int wid = t >> 6, lane = t & 63;
    int wr = wid >> 1, wc = wid & 1;
    int lg = lane >> 4, lr = lane & 15;
    f32x4 acc[4][4] = {};

    int srow = wid * 32 + (lane >> 2);
    int scol = (lane & 3) * 8;
    const unsigned short* Ag = A + (size_t)(m0 + srow) * K + scol;
    const unsigned short* Bg = Bt + (size_t)(n0 + srow) * K + scol;

    auto stage = [&](int buf, int kt) {
        int k0 = (kb + kt) * BK;
        char* Al = (char*)As[buf] + wid * 2048;
        char* Bl = (char*)Bs[buf] + wid * 2048;
        gload16(Ag + k0, Al);
        gload16(Ag + k0 + (size_t)16 * K, Al + 1024);
        gload16(Bg + k0, Bl);
        gload16(Bg + k0 + (size_t)16 * K, Bl + 1024);
    };
    int nt = Kc / BK;
    stage(0, 0);
    if (nt > 1) stage(1, 1);
    for (int k = 0; k < nt; k++) {
        int cur = k % 3;
        if (k + 2 < nt) {
            stage((k + 2) % 3, k + 2);
            asm volatile("s_waitcnt vmcnt(8)" ::: "memory");
        } else if (k + 1 < nt) {
            asm volatile("s_waitcnt vmcnt(4)" ::: "memory");
        } else {
            asm volatile("s_waitcnt vmcnt(0)" ::: "memory");
        }
        __builtin_amdgcn_sched_barrier(0);
        __builtin_amdgcn_s_barrier();
        const unsigned short* Ab = As[cur];
        const unsigned short* Bbp = Bs[cur];
        s16x8 af[4], bfr[4];
#pragma unroll
        for (int i = 0; i < 4; i++) {
            af[i]  = *(const s16x8*)&Ab[(wr * 64 + i * 16 + lr) * 32 + lg * 8];
            bfr[i] = *(const s16x8*)&Bbp[(wc * 64 + i * 16 + lr) * 32 + lg * 8];
        }
#pragma unroll
        for (int mi = 0; mi < 4; mi++)
#pragma unroll
            for (int ni = 0; ni < 4; ni++)
                acc[mi][ni] = __builtin_amdgcn_mfma_f32_16x16x32_bf16(
                    af[mi], bfr[ni], acc[mi][ni], 0, 0, 0);
        __builtin_amdgcn_s_barrier();
    }

    float* po = part + (size_t)kz * M * N;
    int mrow = m0 + wr * 64;
    int ncol = n0 + wc * 64;
#pragma unroll
    for (int mi = 0; mi < 4; mi++)
#pragma unroll
        for (int ni = 0; ni < 4; ni++) {
            int nn = ncol + ni * 16 + lr;
#pragma unroll
            for (int r = 0; r < 4; r++) {
                int mm = mrow + mi * 16 + lg * 4 + r;
                po[(size_t)mm * N + nn] = acc[mi][ni][r];
            }
        }
}

// ------- split-K=4 reduce + residual-gather + LayerNorm2 (sorted order) -------
__global__ __launch_bounds__(256) void k_reduce4_ln(const float* __restrict__ part,
                                                    const float* __restrict__ bias,
                                                    const float* __restrict__ x,
                                                    const int* __restrict__ s2o,
                                                    const float* __restrict__ g,
                                                    const float* __restrict__ be,
                                                    float* __restrict__ x2,
                                                    unsigned short* __restrict__ xn,
                                                    int MN) {
    int wid = threadIdx.x >> 6, lane = threadIdx.x & 63;
    int row = blockIdx.x * 4 + wid;
    int orig = (row & ~(Nn - 1)) | s2o[row];
    size_t base = (size_t)row * Dd;
    size_t obase = (size_t)orig * Dd;
    f32x4 v[3];
    float s = 0.f, sq = 0.f;
#pragma unroll
    for (int j = 0; j < 3; j++) {
        int col = j * 256 + lane * 4;
        f32x4 a0 = *(const f32x4*)(part + base + col);
        f32x4 a1 = *(const f32x4*)(part + (size_t)MN + base + col);
        f32x4 a2 = *(const f32x4*)(part + 2 * (size_t)MN + base + col);
        f32x4 a3 = *(const f32x4*)(part + 3 * (size_t)MN + base + col);
        f32x4 r = *(const f32x4*)(x + obase + col);
        f32x4 bs = *(const f32x4*)(bias + col);
#pragma unroll
        for (int q = 0; q < 4; q++) {
            v[j][q] = (a0[q] + a1[q]) + (a2[q] + a3[q]) + bs[q] + r[q];
            s += v[j][q];
            sq += v[j][q] * v[j][q];
        }
        *(f32x4*)(x2 + base + col) = v[j];
    }
    s = wred_sum(s); sq = wred_sum(sq);
    s = __shfl(s, 0, 64); sq = __shfl(sq, 0, 64);
    float mean = s * (1.f / Dd);
    float var = sq * (1.f / Dd) - mean * mean;
    float rs = rsqrtf(var + 1e-5f);
#pragma unroll
    for (int j = 0; j < 3; j++) {
        int col = j * 256 + lane * 4;
        f32x4 gg = *(const f32x4*)(g + col);
        f32x4 bb = *(const f32x4*)(be + col);
        ushort4 o;
        o.x = f2bf((v[j][0] - mean) * rs * gg[0] + bb[0]);
        o.y = f2bf((v[j][1] - mean) * rs * gg[1] + bb[1]);
        o.z = f2bf((v[j][2] - mean) * rs * gg[2] + bb[2]);
        o.w = f2bf((v[j][3] - mean) * rs * gg[3] + bb[3]);
        *(ushort4*)(xn + base + col) = o;
    }
}

// ------- split-K=4 reduce + scatter to ORIGINAL order (final output, f32) -------
__global__ __launch_bounds__(256) void k_reduce4_sc(const float* __restrict__ part,
                                                    const float* __restrict__ bias,
                                                    const float* __restrict__ res,
                                                    const int* __restrict__ s2o,
                                                    float* __restrict__ out,
                                                    int MN) {
    int wid = threadIdx.x >> 6, lane = threadIdx.x & 63;
    int row = blockIdx.x * 4 + wid;
    int orig = (row & ~(Nn - 1)) | s2o[row];
    size_t base = (size_t)row * Dd;
    size_t obase = (size_t)orig * Dd;
#pragma unroll
    for (int j = 0; j < 3; j++) {
        int col = j * 256 + lane * 4;
        f32x4 a0 = *(const f32x4*)(part + base + col);
        f32x4 a1 = *(const f32x4*)(part + (size_t)MN + base + col);
        f32x4 a2 = *(const f32x4*)(part + 2 * (size_t)MN + base + col);
        f32x4 a3 = *(const f32x4*)(part + 3 * (size_t)MN + base + col);
        f32x4 r = *(const f32x4*)(res + base + col);
        f32x4 bs = *(const f32x4*)(bias + col);
        f32x4 o;
#pragma unroll
        for (int q = 0; q < 4; q++)
            o[q] = (a0[q] + a1[q]) + (a2[q] + a3[q]) + bs[q] + r[q];
        *(f32x4*)(out + obase + col) = o;
    }
}

// ---------------- sparse masked flash attention (sorted order throughout) ----------------
constexpr float SC2 = 0.125f * 1.44269504088896340736f;
constexpr float PMASK = -3.0e38f;
constexpr float MINIT = -1.0e30f;

__global__ __launch_bounds__(256) void k_attn(const unsigned short* __restrict__ qkv,
                                              const unsigned short* __restrict__ VtT,
                                              const uint2* __restrict__ mb,
                                              const int* __restrict__ tl,
                                              unsigned short* __restrict__ out) {
    int lin = blockIdx.x;                       // 768 = 8 XCD chunks of 96
    int id = (lin & 7) * 96 + (lin >> 3);
    int q64 = id & 31;
    int hb = id >> 5;
    int h = hb % Hh, b = hb / Hh;
    int bh = b * Hh + h;

    __shared__ __align__(16) char sm[2 * 16384 + 4 * 2048];

    int t = threadIdx.x, wid = t >> 6, lane = t & 63;
    int lg = lane >> 4, lr = lane & 15;
    int sw = lr & 7;
    int qbase = q64 * 64 + wid * 16;

    const unsigned short* Qb = qkv + ((size_t)b * Nn + qbase + lr) * QKVN + h * 64;
    s16x8 qf0 = *(const s16x8*)(Qb + lg * 8);
    s16x8 qf1 = *(const s16x8*)(Qb + 32 + lg * 8);

    const uint2* mrow = mb + ((size_t)(b * Nn + qbase + lr) << 5);
    const int* tle = tl + (b * 32 + q64) * 33;
    int tlv = (lane < 33) ? tle[lane] : 0;
    int cnt = __shfl(tlv, 0, 64);

    int srow = lane >> 3, sch = lane & 7;
    int krow = wid * 8 + srow;
    int kx = sch ^ (krow & 7);
    const unsigned short* Kg0 = qkv + ((size_t)b * Nn + krow) * QKVN + Dd + h * 64 + kx * 8;
    const unsigned short* Vg0 = VtT + ((size_t)bh * 64 + krow) * Nn + kx * 8;
    char* pw = sm + 32768 + wid * 2048 + lr * 128;

    float m2 = MINIT, l_run = 0.f;
    f32x4 oacc[4] = {};

    int tid0 = __shfl(tlv, 1, 64);
    uint2 Mw = mrow[tid0];
    {
        char* Kl = sm + wid * 1024;
        gload16(Kg0 + (size_t)(tid0 * 64) * QKVN, Kl);
        gload16(Kg0 + (size_t)(tid0 * 64 + 32) * QKVN, Kl + 4096);
        char* Vl = sm + 8192 + wid * 1024;
        gload16(Vg0 + tid0 * 64, Vl);
        gload16(Vg0 + tid0 * 64 + 32 * (size_t)Nn, Vl + 4096);
    }
    __syncthreads();

    for (int ti = 0; ti < cnt; ti++) {
        int cur = ti & 1;
        uint2 MwN;
        if (ti + 1 < cnt) {
            int tidn = __shfl(tlv, 2 + ti, 64);
            char* Kl = sm + (cur ^ 1) * 16384 + wid * 1024;
            gload16(Kg0 + (size_t)(tidn * 64) * QKVN, Kl);
            gload16(Kg0 + (size_t)(tidn * 64 + 32) * QKVN, Kl + 4096);
            char* Vl = sm + (cur ^ 1) * 16384 + 8192 + wid * 1024;
            gload16(Vg0 + tidn * 64, Vl);
            gload16(Vg0 + tidn * 64 + 32 * (size_t)Nn, Vl + 4096);
            MwN = mrow[tidn];
        }

        if (__any((Mw.x | Mw.y) != 0)) {
            const char* Kbuf = sm + cur * 16384;
            const char* Vbuf = Kbuf + 8192;

            __builtin_amdgcn_s_setprio(1);
            f32x4 st[4];
#pragma unroll
            for (int s = 0; s < 4; s++) {
                const char* kr = Kbuf + (s * 16 + lr) * 128;
                s16x8 kf0 = *(const s16x8*)(kr + ((lg ^ sw) << 4));
                s16x8 kf1 = *(const s16x8*)(kr + (((4 + lg) ^ sw) << 4));
                f32x4 z = {};
                z = __builtin_amdgcn_mfma_f32_16x16x32_bf16(kf0, qf0, z, 0, 0, 0);
                st[s] = __builtin_amdgcn_mfma_f32_16x16x32_bf16(kf1, qf1, z, 0, 0, 0);
            }
            __builtin_amdgcn_s_setprio(0);

            float p[4][4];
            float mt = PMASK;
#pragma unroll
            for (int s = 0; s < 4; s++) {
                unsigned int wsel = (s < 2) ? Mw.x : Mw.y;
#pragma unroll
                for (int r = 0; r < 4; r++) {
                    float sv = st[s][r] * SC2;
                    unsigned int bit = (wsel >> ((s & 1) * 16 + lg * 4 + r)) & 1u;
                    p[s][r] = bit ? sv : PMASK;
                    mt = fmaxf(mt, p[s][r]);
                }
            }
            mt = fmaxf(mt, __shfl_xor(mt, 16, 64));
            mt = fmaxf(mt, __shfl_xor(mt, 32, 64));

            if (!__all(mt <= m2 + 11.5416f)) {
                float mn2 = fmaxf(m2, mt);
                float fac = __builtin_amdgcn_exp2f(m2 - mn2);
                l_run *= fac;
                m2 = mn2;
                float fr[4];
#pragma unroll
                for (int r = 0; r < 4; r++) fr[r] = __shfl(fac, (lane & 48) + lg * 4 + r, 64);
#pragma unroll
                for (int dt = 0; dt < 4; dt++)
#pragma unroll
                    for (int r = 0; r < 4; r++) oacc[dt][r] *= fr[r];
            }

            float lt = 0.f;
#pragma unroll
            for (int s = 0; s < 4; s++)
#pragma unroll
                for (int r = 0; r < 4; r++) {
                    p[s][r] = __builtin_amdgcn_exp2f(p[s][r] - m2);
                    lt += p[s][r];
                }
            lt += __shfl_xor(lt, 16, 64);
            lt += __shfl_xor(lt, 32, 64);
            l_run += lt;

#pragma unroll
            for (int s = 0; s < 4; s++) {
                unsigned int lo = (unsigned int)f2bf(p[s][0]) | ((unsigned int)f2bf(p[s][1]) << 16);
                unsigned int hi = (unsigned int)f2bf(p[s][2]) | ((unsigned int)f2bf(p[s][3]) << 16);
                unsigned long long u = (unsigned long long)lo | ((unsigned long long)hi << 32);
                int chunk = (s * 2 + (lg >> 1)) ^ sw;
                *(unsigned long long*)(pw + (chunk << 4) + (lg & 1) * 8) = u;
            }

            __builtin_amdgcn_s_setprio(1);
#pragma unroll
            for (int c = 0; c < 2; c++) {
                s16x8 pf = *(const s16x8*)(pw + (((c * 4 + lg) ^ sw) << 4));
#pragma unroll
                for (int dt = 0; dt < 4; dt++) {
                    const char* vr = Vbuf + (dt * 16 + lr) * 128;
                    s16x8 vf = *(const s16x8*)(vr + (((c * 4 + lg) ^ sw) << 4));
                    oacc[dt] = __builtin_amdgcn_mfma_f32_16x16x32_bf16(pf, vf, oacc[dt], 0, 0, 0);
                }
            }
            __builtin_amdgcn_s_setprio(0);
        }

        __syncthreads();
        Mw = MwN;
    }

    float lr4[4];
#pragma unroll
    for (int r = 0; r < 4; r++)
        lr4[r] = __shfl(l_run, (lane & 48) + lg * 4 + r, 64);
#pragma unroll
    for (int dt = 0; dt < 4; dt++)
#pragma unroll
        for (int r = 0; r < 4; r++) {
            float v = oacc[dt][r] / lr4[r];
            out[((size_t)b * Nn + qbase + lg * 4 + r) * Dd + h * 64 + dt * 16 + lr] = f2bf(v);
        }
}

// ---------------- launch ----------------
extern "C" void kernel_launch(void* const* d_in, const int* in_sizes, int n_in,
                              void* d_out, int out_size, void* d_ws, size_t ws_size,
                              hipStream_t stream) {
    const float* x      = (const float*)d_in[0];
    const float* coords = (const float*)d_in[1];
    const float* w_qkv  = (const float*)d_in[2];
    const float* b_qkv  = (const float*)d_in[3];
    const float* w_out  = (const float*)d_in[4];
    const float* b_out  = (const float*)d_in[5];
    const float* w_ff1  = (const float*)d_in[6];
    const float* b_ff1  = (const float*)d_in[7];
    const float* w_ff2  = (const float*)d_in[8];
    const float* b_ff2  = (const float*)d_in[9];
    const float* g1     = (const float*)d_in[10];
    const float* beta1  = (const float*)d_in[11];
    const float* g2     = (const float*)d_in[12];
    const float* beta2  = (const float*)d_in[13];

    char* ws = (char*)d_ws;
    size_t off = 0;
    auto alloc = [&](size_t bytes) {
        char* p = ws + off;
        off += (bytes + 255) & ~(size_t)255;
        return p;
    };
    unsigned short* w_qkv_t = (unsigned short*)alloc((size_t)QKVN * Dd * 2);
    unsigned short* w_out_t = (unsigned short*)alloc((size_t)Dd * Dd * 2);
    unsigned short* w_ff1_t = (unsigned short*)alloc((size_t)FFf * Dd * 2);
    unsigned short* w_ff2_t = (unsigned short*)alloc((size_t)Dd * FFf * 2);
    float4*         c4s     = (float4*)alloc((size_t)MTOK * 16);
    int*            s2o     = (int*)alloc((size_t)MTOK * 4);
    unsigned long long* mbits = (unsigned long long*)alloc((size_t)MTOK * 32 * 8);
    int*            tl      = (int*)alloc((size_t)Bb * 32 * 33 * 4);
    unsigned short* xn      = (unsigned short*)alloc((size_t)MTOK * Dd * 2);
    unsigned short* hbuf    = (unsigned short*)alloc((size_t)MTOK * FFf * 2);
    float*          x2      = (float*)alloc((size_t)MTOK * Dd * 4);
    unsigned short* attn_o  = (unsigned short*)alloc((size_t)MTOK * Dd * 2);
    unsigned short* qkv     = (unsigned short*)alloc((size_t)MTOK * QKVN * 2);
    unsigned short* VtT     = (unsigned short*)alloc((size_t)Bb * Hh * 64 * Nn * 2);
    float*          partial = (float*)alloc((size_t)4 * MTOK * Dd * 4);

    k_transpose_all<<<dim3(6912), dim3(32, 8), 0, stream>>>(
        w_qkv, w_out, w_ff1, w_ff2, w_qkv_t, w_out_t, w_ff1_t, w_ff2_t);
    k_sort<<<dim3(Nn / 4, Bb), 256, 0, stream>>>(coords, s2o, c4s);
    k_mask<<<dim3(Nn / 64, 8, Bb), 256, 0, stream>>>(c4s, mbits);
    k_tiles<<<dim3(32, Bb), 64, 0, stream>>>(mbits, tl);

    k_ln_g<<<MTOK, 256, 0, stream>>>(x, s2o, g1, beta1, xn);
    k_gemm_big<0><<<dim3((MTOK / 256) * (QKVN / 128)), 512, 0, stream>>>(
        xn, w_qkv_t, b_qkv, qkv, MTOK, QKVN, Dd);
    k_vt<<<dim3(Nn / 64, Bb * Hh), 256, 0, stream>>>(qkv, VtT);
    k_attn<<<dim3((Nn / 64) * Hh * Bb), 256, 0, stream>>>(
        qkv, VtT, (const uint2*)mbits, tl, attn_o);
    // attn-out projection: split-K=4 + fused reduce+res-gather+LN2 (sorted)
    k_gemm_sk<4><<<dim3((Dd / 128) * (MTOK / 128) * 4), 256, 0, stream>>>(
        attn_o, w_out_t, partial, MTOK, Dd, Dd);
    k_reduce4_ln<<<dim3(MTOK / 4), 256, 0, stream>>>(
        partial, b_out, x, s2o, g2, beta2, x2, xn, MTOK * Dd);
    k_gemm_big<1><<<dim3((MTOK / 256) * (FFf / 128)), 512, 0, stream>>>(
        xn, w_ff1_t, b_ff1, hbuf, MTOK, FFf, Dd);
    // FF2: split-K=4 + reduce + scatter to original order
    k_gemm_sk<4><<<dim3((Dd / 128) * (MTOK / 128) * 4), 256, 0, stream>>>(
        hbuf, w_ff2_t, partial, MTOK, Dd, FFf);
    k_reduce4_sc<<<dim3(MTOK / 4), 256, 0, stream>>>(
        partial, b_ff2, x2, s2o, (float*)d_out, MTOK * Dd);
}

// Round 17
// 200.842 us; speedup vs baseline: 1.1270x; 1.1270x over previous
//
#include <hip/hip_runtime.h>
#include <hip/hip_bf16.h>

typedef unsigned short ushort_t;
typedef __attribute__((ext_vector_type(4))) float f32x4;
typedef __attribute__((ext_vector_type(8))) short s16x8;

#define DEV static __device__ __forceinline__

constexpr int Bb = 2, Nn = 2048, Dd = 768, Hh = 12, FFf = 3072;
constexpr int MTOK = Bb * Nn;           // 4096
constexpr int QKVN = 3 * Dd;            // 2304

DEV unsigned short f2bf(float f) {
    union { float f; unsigned int i; } x; x.f = f;
    unsigned int r = x.i + 0x7FFFu + ((x.i >> 16) & 1u);
    return (unsigned short)(r >> 16);
}

DEV void gload16(const void* g, void* l) {
    __builtin_amdgcn_global_load_lds(
        (const __attribute__((address_space(1))) void*)g,
        (__attribute__((address_space(3))) void*)l, 16, 0, 0);
}

DEV int xcd_swz(int lin, int n) {  // n % 8 == 0 required
    return (lin & 7) * (n >> 3) + (lin >> 3);
}

DEV float gelu_fast(float x) {
    float u = x * (0.7978845608f + 0.0356774081f * x * x);
    float e = __builtin_amdgcn_exp2f(2.885390082f * u);
    float th = 1.f - 2.f / (e + 1.f);
    return 0.5f * x * (1.f + th);
}

// ---------------- all 4 weight transposes in ONE kernel ----------------
__global__ void k_transpose_all(const float* __restrict__ w_qkv, const float* __restrict__ w_out,
                                const float* __restrict__ w_ff1, const float* __restrict__ w_ff2,
                                unsigned short* __restrict__ o_qkv, unsigned short* __restrict__ o_out,
                                unsigned short* __restrict__ o_ff1, unsigned short* __restrict__ o_ff2) {
    __shared__ float t[32][33];
    int id = blockIdx.x;
    const float* in; unsigned short* out; int K, N, tid;
    if (id < 1728)      { in = w_qkv; out = o_qkv; K = 768;  N = 2304; tid = id; }
    else if (id < 2304) { in = w_out; out = o_out; K = 768;  N = 768;  tid = id - 1728; }
    else if (id < 4608) { in = w_ff1; out = o_ff1; K = 768;  N = 3072; tid = id - 2304; }
    else                { in = w_ff2; out = o_ff2; K = 3072; N = 768;  tid = id - 4608; }
    int nbx = N >> 5;
    int bx = (tid % nbx) * 32, by = (tid / nbx) * 32;
    int tx = threadIdx.x, ty = threadIdx.y;
#pragma unroll
    for (int i = 0; i < 4; i++)
        t[ty + 8 * i][tx] = in[(size_t)(by + ty + 8 * i) * N + bx + tx];
    __syncthreads();
#pragma unroll
    for (int i = 0; i < 4; i++)
        out[(size_t)(bx + ty + 8 * i) * K + by + tx] = f2bf(t[tx][ty + 8 * i]);
}

// ---------------- deterministic spatial counting sort ----------------
DEV int cell3(float x, float y, float z) {
    int cx = (int)(x * 0.5f); cx = cx > 4 ? 4 : cx;
    int cy = (int)(y * 0.5f); cy = cy > 4 ? 4 : cy;
    int cz = (int)(z * 0.5f); cz = cz > 4 ? 4 : cz;
    return (cz * 5 + cy) * 5 + cx;
}

__global__ __launch_bounds__(256) void k_sort(const float* __restrict__ coords,
                                              int* __restrict__ s2o,
                                              float4* __restrict__ c4s) {
    int b = blockIdx.y;
    int i = blockIdx.x * 4 + (threadIdx.x >> 6);
    int lane = threadIdx.x & 63;
    const float* cb = coords + (size_t)b * Nn * 3;
    float cix = cb[3 * i], ciy = cb[3 * i + 1], ciz = cb[3 * i + 2];
    int celli = cell3(cix, ciy, ciz);
    int pos = 0;
    for (int it = 0; it < Nn / 64; it++) {
        int j = it * 64 + lane;
        int cj = cell3(cb[3 * j], cb[3 * j + 1], cb[3 * j + 2]);
        bool before = (cj < celli) || (cj == celli && j < i);
        pos += __popcll(__ballot(before));
    }
    if (lane == 0) {
        s2o[b * Nn + pos] = i;
        c4s[b * Nn + pos] = make_float4(cix, ciy, ciz, 0.f);
    }
}

// ---------------- radius mask bits on SORTED coords ----------------
__global__ __launch_bounds__(256) void k_mask(const float4* __restrict__ c4s,
                                              unsigned long long* __restrict__ mb) {
    int qt = blockIdx.x, ks = blockIdx.y, b = blockIdx.z;
    __shared__ float4 ck[256];
    int t = threadIdx.x;
    ck[t] = c4s[b * Nn + ks * 256 + t];
    __syncthreads();
    int r = t >> 2, c = t & 3;
    int q = qt * 64 + r;
    float4 cq = c4s[b * Nn + q];
    unsigned long long w = 0;
#pragma unroll 8
    for (int j = 0; j < 64; j++) {
        float4 k4 = ck[c * 64 + j];
        float dx = __fsub_rn(cq.x, k4.x);
        float dy = __fsub_rn(cq.y, k4.y);
        float dz = __fsub_rn(cq.z, k4.z);
        float d2 = __fadd_rn(__fadd_rn(__fmul_rn(dx, dx), __fmul_rn(dy, dy)),
                             __fmul_rn(dz, dz));
        if (d2 <= 4.0f) w |= 1ull << j;
    }
    mb[((size_t)(b * Nn + q) << 5) + ks * 4 + c] = w;
}

// ---------------- per-64q-block live-tile union lists ----------------
__global__ __launch_bounds__(64) void k_tiles(const unsigned long long* __restrict__ mb,
                                              int* __restrict__ tl) {
    int q64 = blockIdx.x, b = blockIdx.y;
    int lane = threadIdx.x;
    unsigned long long v = 0;
    if (lane < 32) {
        const unsigned long long* base = mb + ((size_t)(b * Nn + q64 * 64) << 5) + lane;
        for (int r = 0; r < 64; r++) v |= base[(size_t)r << 5];
    }
    unsigned long long nz = __ballot(v != 0);
    int idx = __popcll(nz & ((1ull << lane) - 1));
    int* o = tl + (b * 32 + q64) * 33;
    if (v != 0) o[1 + idx] = lane;
    if (lane == 0) o[0] = __popcll(nz);
}

// ---------------- V transpose from SORTED qkv: VtT[(b*H+h)*64+d][ns] ----------------
__global__ __launch_bounds__(256) void k_vt(const unsigned short* __restrict__ qkv,
                                            unsigned short* __restrict__ VtT) {
    __shared__ unsigned short Ld[64][72];
    int ns0 = blockIdx.x * 64;
    int bh = blockIdx.y;
    int b = bh / Hh, h = bh % Hh;
    int t = threadIdx.x;
#pragma unroll
    for (int i = 0; i < 2; i++) {
        int item = t + 256 * i;
        int row = item >> 3, ch = (item & 7) * 8;
        *(s16x8*)&Ld[row][ch] =
            *(const s16x8*)(qkv + ((size_t)b * Nn + ns0 + row) * QKVN + 2 * Dd + h * 64 + ch);
    }
    __syncthreads();
    int vd = (t >> 5) * 8, vkp = (t & 31) * 2;
#pragma unroll
    for (int j = 0; j < 8; j++) {
        unsigned int pack = (unsigned int)Ld[vkp][vd + j] |
                            ((unsigned int)Ld[vkp + 1][vd + j] << 16);
        *(unsigned int*)((char*)VtT +
                         (((size_t)bh * 64 + vd + j) * Nn + ns0 + vkp) * 2) = pack;
    }
}

// ---------------- LayerNorm with row gather (sorted order) ----------------
DEV float wred_sum(float v) {
#pragma unroll
    for (int o = 32; o; o >>= 1) v += __shfl_down(v, o, 64);
    return v;
}

__global__ __launch_bounds__(256) void k_ln_g(const float* __restrict__ x,
                                              const int* __restrict__ s2o,
                                              const float* __restrict__ g,
                                              const float* __restrict__ be,
                                              unsigned short* __restrict__ out) {
    int row = blockIdx.x;
    int orig = (row & ~(Nn - 1)) | s2o[row];
    const float* xr = x + (size_t)orig * Dd;
    int t = threadIdx.x;
    float v0 = xr[t], v1 = xr[t + 256], v2 = xr[t + 512];
    float s = v0 + v1 + v2;
    float sq = v0 * v0 + v1 * v1 + v2 * v2;
    __shared__ float r1[4], r2[4];
    float ws = wred_sum(s), wq = wred_sum(sq);
    int wid = t >> 6, lane = t & 63;
    if (lane == 0) { r1[wid] = ws; r2[wid] = wq; }
    __syncthreads();
    s = r1[0] + r1[1] + r1[2] + r1[3];
    sq = r2[0] + r2[1] + r2[2] + r2[3];
    float mean = s * (1.f / Dd);
    float var = sq * (1.f / Dd) - mean * mean;
    float rs = rsqrtf(var + 1e-5f);
    unsigned short* orow = out + (size_t)row * Dd;
    orow[t]       = f2bf((v0 - mean) * rs * g[t]       + be[t]);
    orow[t + 256] = f2bf((v1 - mean) * rs * g[t + 256] + be[t + 256]);
    orow[t + 512] = f2bf((v2 - mean) * rs * g[t + 512] + be[t + 512]);
}

// ------- pipelined GEMM core (round-13 proven best): 128x128, TRIPLE-buf, depth-2 -------
#define GEMM_PIPE_LOOP(NT)                                                              \
    stage(0, 0);                                                                        \
    if ((NT) > 1) stage(1, 1);                                                          \
    for (int t = 0; t < (NT); t++) {                                                    \
        int cur = t % 3;                                                                \
        if (t + 2 < (NT)) {                                                             \
            stage((t + 2) % 3, t + 2);                                                  \
            asm volatile("s_waitcnt vmcnt(8)" ::: "memory");                            \
        } else if (t + 1 < (NT)) {                                                      \
            asm volatile("s_waitcnt vmcnt(4)" ::: "memory");                            \
        } else {                                                                        \
            asm volatile("s_waitcnt vmcnt(0)" ::: "memory");                            \
        }                                                                               \
        __builtin_amdgcn_sched_barrier(0);                                              \
        __builtin_amdgcn_s_barrier();                                                   \
        const unsigned short* Ab = As[cur];                                             \
        const unsigned short* Bbp = Bs[cur];                                            \
        s16x8 af[4], bfr[4];                                                            \
        _Pragma("unroll")                                                               \
        for (int i = 0; i < 4; i++) {                                                   \
            af[i]  = *(const s16x8*)&Ab[(wr * 64 + i * 16 + lr) * 32 + lg * 8];         \
            bfr[i] = *(const s16x8*)&Bbp[(wc * 64 + i * 16 + lr) * 32 + lg * 8];        \
        }                                                                               \
        _Pragma("unroll")                                                               \
        for (int mi = 0; mi < 4; mi++)                                                  \
            _Pragma("unroll")                                                           \
            for (int ni = 0; ni < 4; ni++)                                              \
                acc[mi][ni] = __builtin_amdgcn_mfma_f32_16x16x32_bf16(                  \
                    af[mi], bfr[ni], acc[mi][ni], 0, 0, 0);                             \
        __builtin_amdgcn_s_barrier();                                                   \
    }

// EPI 0: out bf16 = A@B + bias ; 1: gelu
template <int EPI>
__global__ __launch_bounds__(256) void k_gemm(const unsigned short* __restrict__ A,
                                              const unsigned short* __restrict__ Bt,
                                              const float* __restrict__ bias,
                                              unsigned short* __restrict__ outp,
                                              int M, int N, int K) {
    constexpr int BM = 128, BN = 128, BK = 32;
    __shared__ unsigned short As[3][BM * BK];
    __shared__ unsigned short Bs[3][BN * BK];
    int NB = N >> 7;
    int id = xcd_swz(blockIdx.x, gridDim.x);
    int m0 = (id / NB) * BM, n0 = (id % NB) * BN;
    int t = threadIdx.x;
    int wid = t >> 6, lane = t & 63;
    int wr = wid >> 1, wc = wid & 1;
    int lg = lane >> 4, lr = lane & 15;
    f32x4 acc[4][4] = {};

    int srow = wid * 32 + (lane >> 2);
    int scol = (lane & 3) * 8;
    const unsigned short* Ag = A + (size_t)(m0 + srow) * K + scol;
    const unsigned short* Bg = Bt + (size_t)(n0 + srow) * K + scol;

    auto stage = [&](int buf, int kt) {
        int k0 = kt * BK;
        char* Al = (char*)As[buf] + wid * 2048;
        char* Bl = (char*)Bs[buf] + wid * 2048;
        gload16(Ag + k0, Al);
        gload16(Ag + k0 + (size_t)16 * K, Al + 1024);
        gload16(Bg + k0, Bl);
        gload16(Bg + k0 + (size_t)16 * K, Bl + 1024);
    };
    int nt = K / BK;
    GEMM_PIPE_LOOP(nt)

    int mrow = m0 + wr * 64;
    int ncol = n0 + wc * 64;
#pragma unroll
    for (int mi = 0; mi < 4; mi++) {
#pragma unroll
        for (int ni = 0; ni < 4; ni++) {
            int nn = ncol + ni * 16 + lr;
            float bs = bias[nn];
#pragma unroll
            for (int r = 0; r < 4; r++) {
                int mm = mrow + mi * 16 + lg * 4 + r;
                float v = acc[mi][ni][r] + bs;
                if (EPI == 1) v = gelu_fast(v);
                outp[(size_t)mm * N + nn] = f2bf(v);
            }
        }
    }
}

// ---------------- split-K GEMM (128^2, BK=32, triple-buf, depth-2): partial f32 ----------------
template <int SPLIT>
__global__ __launch_bounds__(256) void k_gemm_sk(const unsigned short* __restrict__ A,
                                                 const unsigned short* __restrict__ Bt,
                                                 float* __restrict__ part,
                                                 int M, int N, int K) {
    constexpr int BM = 128, BN = 128, BK = 32;
    __shared__ unsigned short As[3][BM * BK];
    __shared__ unsigned short Bs[3][BN * BK];
    int NB = N >> 7, MB = M >> 7;
    int id = xcd_swz(blockIdx.x, gridDim.x);
    int nb = id % NB;
    int mbk = (id / NB) % MB;
    int kz = id / (NB * MB);
    int m0 = mbk * BM, n0 = nb * BN;
    int Kc = K / SPLIT, kb = kz * (Kc / BK);
    int t = threadIdx.x;
    int wid = t >> 6, lane = t & 63;
    int wr = wid >> 1, wc = wid & 1;
    int lg = lane >> 4, lr = lane & 15;
    f32x4 acc[4][4] = {};

    int srow = wid * 32 + (lane >> 2);
    int scol = (lane & 3) * 8;
    const unsigned short* Ag = A + (size_t)(m0 + srow) * K + scol;
    const unsigned short* Bg = Bt + (size_t)(n0 + srow) * K + scol;

    auto stage = [&](int buf, int kt) {
        int k0 = (kb + kt) * BK;
        char* Al = (char*)As[buf] + wid * 2048;
        char* Bl = (char*)Bs[buf] + wid * 2048;
        gload16(Ag + k0, Al);
        gload16(Ag + k0 + (size_t)16 * K, Al + 1024);
        gload16(Bg + k0, Bl);
        gload16(Bg + k0 + (size_t)16 * K, Bl + 1024);
    };
    int nt = Kc / BK;
    GEMM_PIPE_LOOP(nt)

    float* po = part + (size_t)kz * M * N;
    int mrow = m0 + wr * 64;
    int ncol = n0 + wc * 64;
#pragma unroll
    for (int mi = 0; mi < 4; mi++)
#pragma unroll
        for (int ni = 0; ni < 4; ni++) {
            int nn = ncol + ni * 16 + lr;
#pragma unroll
            for (int r = 0; r < 4; r++) {
                int mm = mrow + mi * 16 + lg * 4 + r;
                po[(size_t)mm * N + nn] = acc[mi][ni][r];
            }
        }
}

// ------- split-K=4 reduce + residual-gather + LayerNorm2 (sorted order) -------
__global__ __launch_bounds__(256) void k_reduce4_ln(const float* __restrict__ part,
                                                    const float* __restrict__ bias,
                                                    const float* __restrict__ x,
                                                    const int* __restrict__ s2o,
                                                    const float* __restrict__ g,
                                                    const float* __restrict__ be,
                                                    float* __restrict__ x2,
                                                    unsigned short* __restrict__ xn,
                                                    int MN) {
    int wid = threadIdx.x >> 6, lane = threadIdx.x & 63;
    int row = blockIdx.x * 4 + wid;
    int orig = (row & ~(Nn - 1)) | s2o[row];
    size_t base = (size_t)row * Dd;
    size_t obase = (size_t)orig * Dd;
    f32x4 v[3];
    float s = 0.f, sq = 0.f;
#pragma unroll
    for (int j = 0; j < 3; j++) {
        int col = j * 256 + lane * 4;
        f32x4 a0 = *(const f32x4*)(part + base + col);
        f32x4 a1 = *(const f32x4*)(part + (size_t)MN + base + col);
        f32x4 a2 = *(const f32x4*)(part + 2 * (size_t)MN + base + col);
        f32x4 a3 = *(const f32x4*)(part + 3 * (size_t)MN + base + col);
        f32x4 r = *(const f32x4*)(x + obase + col);
        f32x4 bs = *(const f32x4*)(bias + col);
#pragma unroll
        for (int q = 0; q < 4; q++) {
            v[j][q] = (a0[q] + a1[q]) + (a2[q] + a3[q]) + bs[q] + r[q];
            s += v[j][q];
            sq += v[j][q] * v[j][q];
        }
        *(f32x4*)(x2 + base + col) = v[j];
    }
    s = wred_sum(s); sq = wred_sum(sq);
    s = __shfl(s, 0, 64); sq = __shfl(sq, 0, 64);
    float mean = s * (1.f / Dd);
    float var = sq * (1.f / Dd) - mean * mean;
    float rs = rsqrtf(var + 1e-5f);
#pragma unroll
    for (int j = 0; j < 3; j++) {
        int col = j * 256 + lane * 4;
        f32x4 gg = *(const f32x4*)(g + col);
        f32x4 bb = *(const f32x4*)(be + col);
        ushort4 o;
        o.x = f2bf((v[j][0] - mean) * rs * gg[0] + bb[0]);
        o.y = f2bf((v[j][1] - mean) * rs * gg[1] + bb[1]);
        o.z = f2bf((v[j][2] - mean) * rs * gg[2] + bb[2]);
        o.w = f2bf((v[j][3] - mean) * rs * gg[3] + bb[3]);
        *(ushort4*)(xn + base + col) = o;
    }
}

// ------- split-K=4 reduce + scatter to ORIGINAL order (final output, f32) -------
__global__ __launch_bounds__(256) void k_reduce4_sc(const float* __restrict__ part,
                                                    const float* __restrict__ bias,
                                                    const float* __restrict__ res,
                                                    const int* __restrict__ s2o,
                                                    float* __restrict__ out,
                                                    int MN) {
    int wid = threadIdx.x >> 6, lane = threadIdx.x & 63;
    int row = blockIdx.x * 4 + wid;
    int orig = (row & ~(Nn - 1)) | s2o[row];
    size_t base = (size_t)row * Dd;
    size_t obase = (size_t)orig * Dd;
#pragma unroll
    for (int j = 0; j < 3; j++) {
        int col = j * 256 + lane * 4;
        f32x4 a0 = *(const f32x4*)(part + base + col);
        f32x4 a1 = *(const f32x4*)(part + (size_t)MN + base + col);
        f32x4 a2 = *(const f32x4*)(part + 2 * (size_t)MN + base + col);
        f32x4 a3 = *(const f32x4*)(part + 3 * (size_t)MN + base + col);
        f32x4 r = *(const f32x4*)(res + base + col);
        f32x4 bs = *(const f32x4*)(bias + col);
        f32x4 o;
#pragma unroll
        for (int q = 0; q < 4; q++)
            o[q] = (a0[q] + a1[q]) + (a2[q] + a3[q]) + bs[q] + r[q];
        *(f32x4*)(out + obase + col) = o;
    }
}

// ---------------- sparse masked flash attention (sorted order throughout) ----------------
constexpr float SC2 = 0.125f * 1.44269504088896340736f;
constexpr float PMASK = -3.0e38f;
constexpr float MINIT = -1.0e30f;

__global__ __launch_bounds__(256) void k_attn(const unsigned short* __restrict__ qkv,
                                              const unsigned short* __restrict__ VtT,
                                              const uint2* __restrict__ mb,
                                              const int* __restrict__ tl,
                                              unsigned short* __restrict__ out) {
    int lin = blockIdx.x;                       // 768 = 8 XCD chunks of 96
    int id = (lin & 7) * 96 + (lin >> 3);
    int q64 = id & 31;
    int hb = id >> 5;
    int h = hb % Hh, b = hb / Hh;
    int bh = b * Hh + h;

    __shared__ __align__(16) char sm[2 * 16384 + 4 * 2048];

    int t = threadIdx.x, wid = t >> 6, lane = t & 63;
    int lg = lane >> 4, lr = lane & 15;
    int sw = lr & 7;
    int qbase = q64 * 64 + wid * 16;

    const unsigned short* Qb = qkv + ((size_t)b * Nn + qbase + lr) * QKVN + h * 64;
    s16x8 qf0 = *(const s16x8*)(Qb + lg * 8);
    s16x8 qf1 = *(const s16x8*)(Qb + 32 + lg * 8);

    const uint2* mrow = mb + ((size_t)(b * Nn + qbase + lr) << 5);
    const int* tle = tl + (b * 32 + q64) * 33;
    int tlv = (lane < 33) ? tle[lane] : 0;
    int cnt = __shfl(tlv, 0, 64);

    int srow = lane >> 3, sch = lane & 7;
    int krow = wid * 8 + srow;
    int kx = sch ^ (krow & 7);
    const unsigned short* Kg0 = qkv + ((size_t)b * Nn + krow) * QKVN + Dd + h * 64 + kx * 8;
    const unsigned short* Vg0 = VtT + ((size_t)bh * 64 + krow) * Nn + kx * 8;
    char* pw = sm + 32768 + wid * 2048 + lr * 128;

    float m2 = MINIT, l_run = 0.f;
    f32x4 oacc[4] = {};

    int tid0 = __shfl(tlv, 1, 64);
    uint2 Mw = mrow[tid0];
    {
        char* Kl = sm + wid * 1024;
        gload16(Kg0 + (size_t)(tid0 * 64) * QKVN, Kl);
        gload16(Kg0 + (size_t)(tid0 * 64 + 32) * QKVN, Kl + 4096);
        char* Vl = sm + 8192 + wid * 1024;
        gload16(Vg0 + tid0 * 64, Vl);
        gload16(Vg0 + tid0 * 64 + 32 * (size_t)Nn, Vl + 4096);
    }
    __syncthreads();

    for (int ti = 0; ti < cnt; ti++) {
        int cur = ti & 1;
        uint2 MwN;
        if (ti + 1 < cnt) {
            int tidn = __shfl(tlv, 2 + ti, 64);
            char* Kl = sm + (cur ^ 1) * 16384 + wid * 1024;
            gload16(Kg0 + (size_t)(tidn * 64) * QKVN, Kl);
            gload16(Kg0 + (size_t)(tidn * 64 + 32) * QKVN, Kl + 4096);
            char* Vl = sm + (cur ^ 1) * 16384 + 8192 + wid * 1024;
            gload16(Vg0 + tidn * 64, Vl);
            gload16(Vg0 + tidn * 64 + 32 * (size_t)Nn, Vl + 4096);
            MwN = mrow[tidn];
        }

        if (__any((Mw.x | Mw.y) != 0)) {
            const char* Kbuf = sm + cur * 16384;
            const char* Vbuf = Kbuf + 8192;

            __builtin_amdgcn_s_setprio(1);
            f32x4 st[4];
#pragma unroll
            for (int s = 0; s < 4; s++) {
                const char* kr = Kbuf + (s * 16 + lr) * 128;
                s16x8 kf0 = *(const s16x8*)(kr + ((lg ^ sw) << 4));
                s16x8 kf1 = *(const s16x8*)(kr + (((4 + lg) ^ sw) << 4));
                f32x4 z = {};
                z = __builtin_amdgcn_mfma_f32_16x16x32_bf16(kf0, qf0, z, 0, 0, 0);
                st[s] = __builtin_amdgcn_mfma_f32_16x16x32_bf16(kf1, qf1, z, 0, 0, 0);
            }
            __builtin_amdgcn_s_setprio(0);

            float p[4][4];
            float mt = PMASK;
#pragma unroll
            for (int s = 0; s < 4; s++) {
                unsigned int wsel = (s < 2) ? Mw.x : Mw.y;
#pragma unroll
                for (int r = 0; r < 4; r++) {
                    float sv = st[s][r] * SC2;
                    unsigned int bit = (wsel >> ((s & 1) * 16 + lg * 4 + r)) & 1u;
                    p[s][r] = bit ? sv : PMASK;
                    mt = fmaxf(mt, p[s][r]);
                }
            }
            mt = fmaxf(mt, __shfl_xor(mt, 16, 64));
            mt = fmaxf(mt, __shfl_xor(mt, 32, 64));

            if (!__all(mt <= m2 + 11.5416f)) {
                float mn2 = fmaxf(m2, mt);
                float fac = __builtin_amdgcn_exp2f(m2 - mn2);
                l_run *= fac;
                m2 = mn2;
                float fr[4];
#pragma unroll
                for (int r = 0; r < 4; r++) fr[r] = __shfl(fac, (lane & 48) + lg * 4 + r, 64);
#pragma unroll
                for (int dt = 0; dt < 4; dt++)
#pragma unroll
                    for (int r = 0; r < 4; r++) oacc[dt][r] *= fr[r];
            }

            float lt = 0.f;
#pragma unroll
            for (int s = 0; s < 4; s++)
#pragma unroll
                for (int r = 0; r < 4; r++) {
                    p[s][r] = __builtin_amdgcn_exp2f(p[s][r] - m2);
                    lt += p[s][r];
                }
            lt += __shfl_xor(lt, 16, 64);
            lt += __shfl_xor(lt, 32, 64);
            l_run += lt;

#pragma unroll
            for (int s = 0; s < 4; s++) {
                unsigned int lo = (unsigned int)f2bf(p[s][0]) | ((unsigned int)f2bf(p[s][1]) << 16);
                unsigned int hi = (unsigned int)f2bf(p[s][2]) | ((unsigned int)f2bf(p[s][3]) << 16);
                unsigned long long u = (unsigned long long)lo | ((unsigned long long)hi << 32);
                int chunk = (s * 2 + (lg >> 1)) ^ sw;
                *(unsigned long long*)(pw + (chunk << 4) + (lg & 1) * 8) = u;
            }

            __builtin_amdgcn_s_setprio(1);
#pragma unroll
            for (int c = 0; c < 2; c++) {
                s16x8 pf = *(const s16x8*)(pw + (((c * 4 + lg) ^ sw) << 4));
#pragma unroll
                for (int dt = 0; dt < 4; dt++) {
                    const char* vr = Vbuf + (dt * 16 + lr) * 128;
                    s16x8 vf = *(const s16x8*)(vr + (((c * 4 + lg) ^ sw) << 4));
                    oacc[dt] = __builtin_amdgcn_mfma_f32_16x16x32_bf16(pf, vf, oacc[dt], 0, 0, 0);
                }
            }
            __builtin_amdgcn_s_setprio(0);
        }

        __syncthreads();
        Mw = MwN;
    }

    float lr4[4];
#pragma unroll
    for (int r = 0; r < 4; r++)
        lr4[r] = __shfl(l_run, (lane & 48) + lg * 4 + r, 64);
#pragma unroll
    for (int dt = 0; dt < 4; dt++)
#pragma unroll
        for (int r = 0; r < 4; r++) {
            float v = oacc[dt][r] / lr4[r];
            out[((size_t)b * Nn + qbase + lg * 4 + r) * Dd + h * 64 + dt * 16 + lr] = f2bf(v);
        }
}

// ---------------- launch ----------------
extern "C" void kernel_launch(void* const* d_in, const int* in_sizes, int n_in,
                              void* d_out, int out_size, void* d_ws, size_t ws_size,
                              hipStream_t stream) {
    const float* x      = (const float*)d_in[0];
    const float* coords = (const float*)d_in[1];
    const float* w_qkv  = (const float*)d_in[2];
    const float* b_qkv  = (const float*)d_in[3];
    const float* w_out  = (const float*)d_in[4];
    const float* b_out  = (const float*)d_in[5];
    const float* w_ff1  = (const float*)d_in[6];
    const float* b_ff1  = (const float*)d_in[7];
    const float* w_ff2  = (const float*)d_in[8];
    const float* b_ff2  = (const float*)d_in[9];
    const float* g1     = (const float*)d_in[10];
    const float* beta1  = (const float*)d_in[11];
    const float* g2     = (const float*)d_in[12];
    const float* beta2  = (const float*)d_in[13];

    char* ws = (char*)d_ws;
    size_t off = 0;
    auto alloc = [&](size_t bytes) {
        char* p = ws + off;
        off += (bytes + 255) & ~(size_t)255;
        return p;
    };
    unsigned short* w_qkv_t = (unsigned short*)alloc((size_t)QKVN * Dd * 2);
    unsigned short* w_out_t = (unsigned short*)alloc((size_t)Dd * Dd * 2);
    unsigned short* w_ff1_t = (unsigned short*)alloc((size_t)FFf * Dd * 2);
    unsigned short* w_ff2_t = (unsigned short*)alloc((size_t)Dd * FFf * 2);
    float4*         c4s     = (float4*)alloc((size_t)MTOK * 16);
    int*            s2o     = (int*)alloc((size_t)MTOK * 4);
    unsigned long long* mbits = (unsigned long long*)alloc((size_t)MTOK * 32 * 8);
    int*            tl      = (int*)alloc((size_t)Bb * 32 * 33 * 4);
    unsigned short* xn      = (unsigned short*)alloc((size_t)MTOK * Dd * 2);
    unsigned short* hbuf    = (unsigned short*)alloc((size_t)MTOK * FFf * 2);
    float*          x2      = (float*)alloc((size_t)MTOK * Dd * 4);
    unsigned short* attn_o  = (unsigned short*)alloc((size_t)MTOK * Dd * 2);
    unsigned short* qkv     = (unsigned short*)alloc((size_t)MTOK * QKVN * 2);
    unsigned short* VtT     = (unsigned short*)alloc((size_t)Bb * Hh * 64 * Nn * 2);
    float*          partial = (float*)alloc((size_t)4 * MTOK * Dd * 4);

    k_transpose_all<<<dim3(6912), dim3(32, 8), 0, stream>>>(
        w_qkv, w_out, w_ff1, w_ff2, w_qkv_t, w_out_t, w_ff1_t, w_ff2_t);
    k_sort<<<dim3(Nn / 4, Bb), 256, 0, stream>>>(coords, s2o, c4s);
    k_mask<<<dim3(Nn / 64, 8, Bb), 256, 0, stream>>>(c4s, mbits);
    k_tiles<<<dim3(32, Bb), 64, 0, stream>>>(mbits, tl);

    k_ln_g<<<MTOK, 256, 0, stream>>>(x, s2o, g1, beta1, xn);
    k_gemm<0><<<dim3((QKVN / 128) * (MTOK / 128)), 256, 0, stream>>>(
        xn, w_qkv_t, b_qkv, qkv, MTOK, QKVN, Dd);
    k_vt<<<dim3(Nn / 64, Bb * Hh), 256, 0, stream>>>(qkv, VtT);
    k_attn<<<dim3((Nn / 64) * Hh * Bb), 256, 0, stream>>>(
        qkv, VtT, (const uint2*)mbits, tl, attn_o);
    // attn-out projection: split-K=4 + fused reduce+res-gather+LN2 (sorted)
    k_gemm_sk<4><<<dim3((Dd / 128) * (MTOK / 128) * 4), 256, 0, stream>>>(
        attn_o, w_out_t, partial, MTOK, Dd, Dd);
    k_reduce4_ln<<<dim3(MTOK / 4), 256, 0, stream>>>(
        partial, b_out, x, s2o, g2, beta2, x2, xn, MTOK * Dd);
    k_gemm<1><<<dim3((FFf / 128) * (MTOK / 128)), 256, 0, stream>>>(
        xn, w_ff1_t, b_ff1, hbuf, MTOK, FFf, Dd);
    // FF2: split-K=4 + reduce + scatter to original order
    k_gemm_sk<4><<<dim3((Dd / 128) * (MTOK / 128) * 4), 256, 0, stream>>>(
        hbuf, w_ff2_t, partial, MTOK, Dd, FFf);
    k_reduce4_sc<<<dim3(MTOK / 4), 256, 0, stream>>>(
        partial, b_ff2, x2, s2o, (float*)d_out, MTOK * Dd);
}